// Round 8
// baseline (158.952 us; speedup 1.0000x reference)
//
#include <hip/hip_runtime.h>

#define D 128
#define NCK 512           // edge chunks (one block each in K1)
#define RPB 64            // rows per bucket
#define CHUNKCAP 1600     // LDS staging per chunk (chunk <= 1563)
#define BCAP 2048         // per-bucket edge capacity (mean 1024, +32 sigma)
#define SCANW 1024        // padded bucket-scan width (nbuck <= 1024)

typedef short short8 __attribute__((ext_vector_type(8)));
typedef float v4f __attribute__((ext_vector_type(4)));
typedef float float2v __attribute__((ext_vector_type(2)));

static __device__ __forceinline__ unsigned short f2bf(float f) {
    unsigned u = __builtin_bit_cast(unsigned, f);
    u = (u + 0x7FFFu + ((u >> 16) & 1u)) >> 16;   // RNE
    return (unsigned short)u;
}

// ---- K1: per-chunk LDS counting-sort by bucket + Wt prep -------------------
// Block c sorts edges [c*chunk, ...) by bucket (r>>6) into the contiguous
// region sortedB[c*chunk ...], writing cntT/offT[c][b]. No global atomics.
__global__ __launch_bounds__(256) void binsort_prep(
    const int* __restrict__ rows, const int* __restrict__ cols,
    const float* __restrict__ vals,
    const float* __restrict__ W, const float* __restrict__ Wr,
    unsigned short* __restrict__ Wt,
    int* __restrict__ cntT, int* __restrict__ offT, int2* __restrict__ sortedB,
    int E, int nbuck, int chunk)
{
    __shared__ int hist[SCANW];
    __shared__ int cur[SCANW];
    __shared__ int2 stg[CHUNKCAP];
    const int t = threadIdx.x, c = blockIdx.x;

    if (t < 64) {                        // Wt prep: 32768 elems over 512 blocks
        const int gid = c * 64 + t;
        const int k  = gid >> 8;
        const int nn = gid & 255;
        const float v = (nn < D) ? W[k * D + nn] : Wr[k * D + (nn - D)];
        Wt[nn * D + k] = f2bf(v);
    }
    #pragma unroll
    for (int j = 0; j < SCANW / 256; ++j) hist[t + j * 256] = 0;
    __syncthreads();

    const int base = c * chunk;
    const int endv = min(base + chunk, E);
    for (int e = base + t; e < endv; e += 256)
        atomicAdd(&hist[rows[e] >> 6], 1);
    __syncthreads();

    int cl_[4];
    #pragma unroll
    for (int j = 0; j < 4; ++j) {
        const int idx = t + j * 256;
        cl_[j] = hist[idx];
        if (idx < nbuck) cntT[(size_t)c * nbuck + idx] = cl_[j];
    }
    // inclusive scan over SCANW entries, 4 per thread (double-sync H-S)
    for (int off = 1; off < SCANW; off <<= 1) {
        int a[4];
        #pragma unroll
        for (int j = 0; j < 4; ++j) {
            const int idx = t + j * 256;
            a[j] = (idx >= off) ? hist[idx - off] : 0;
        }
        __syncthreads();
        #pragma unroll
        for (int j = 0; j < 4; ++j) hist[t + j * 256] += a[j];
        __syncthreads();
    }
    #pragma unroll
    for (int j = 0; j < 4; ++j) {
        const int idx = t + j * 256;
        const int ex = hist[idx] - cl_[j];           // exclusive
        cur[idx] = ex;
        if (idx < nbuck) offT[(size_t)c * nbuck + idx] = ex;
    }
    __syncthreads();

    for (int e = base + t; e < endv; e += 256) {
        const int r  = rows[e];
        const int cc = cols[e];
        const float v = vals[e];
        const int pos = atomicAdd(&cur[r >> 6], 1);
        stg[pos] = make_int2(((r & (RPB - 1)) << 16) | cc, __float_as_int(v));
    }
    __syncthreads();

    const int n = endv - base;
    for (int k = t; k < n; k += 256)
        sortedB[(size_t)base + k] = stg[k];   // contiguous, full-line writes
}

// ---- K2: dual GEMM: support(bf16)=x@W, rootbuf(bf16)=x@Wr ------------------
__global__ __launch_bounds__(256) void gemm_dual(
    const float* __restrict__ x, const unsigned short* __restrict__ Wt,
    unsigned short* __restrict__ support, unsigned short* __restrict__ rootbuf,
    int M)
{
    __shared__ unsigned short As[64][136];
    const int tid = threadIdx.x;
    const int w = tid >> 6;
    const int lane = tid & 63;
    const int nl = lane & 15, quad = lane >> 4;
    const int rowBase = (int)blockIdx.x * 64;

    {
        const int r = tid & 63;
        const int seg = tid >> 6;
        const int row = rowBase + r;
        unsigned short tmp[32];
        if (row < M) {
            const float4* src = (const float4*)(x + (size_t)row * D + seg * 32);
            #pragma unroll
            for (int j = 0; j < 8; ++j) {
                const float4 v = src[j];
                tmp[j * 4 + 0] = f2bf(v.x); tmp[j * 4 + 1] = f2bf(v.y);
                tmp[j * 4 + 2] = f2bf(v.z); tmp[j * 4 + 3] = f2bf(v.w);
            }
        } else {
            #pragma unroll
            for (int j = 0; j < 32; ++j) tmp[j] = 0;
        }
        #pragma unroll
        for (int j = 0; j < 4; ++j)
            *(short8*)&As[r][seg * 32 + j * 8] = *(const short8*)&tmp[j * 8];
    }

    short8 bfrag[4][4];
    {
        const unsigned short* wbase = Wt + (size_t)(w * 64 + nl) * D + quad * 8;
        #pragma unroll
        for (int nt = 0; nt < 4; ++nt)
            #pragma unroll
            for (int c = 0; c < 4; ++c)
                bfrag[c][nt] = *(const short8*)(wbase + (size_t)nt * 16 * D + c * 32);
    }
    __syncthreads();

    v4f acc[4][4] = {};
    #pragma unroll
    for (int c = 0; c < 4; ++c) {
        short8 afr[4];
        #pragma unroll
        for (int mt = 0; mt < 4; ++mt)
            afr[mt] = *(const short8*)&As[mt * 16 + nl][c * 32 + quad * 8];
        #pragma unroll
        for (int mt = 0; mt < 4; ++mt)
            #pragma unroll
            for (int nt = 0; nt < 4; ++nt)
                acc[mt][nt] = __builtin_amdgcn_mfma_f32_16x16x32_bf16(
                    afr[mt], bfrag[c][nt], acc[mt][nt], 0, 0, 0);
    }

    const int cbase = (w & 1) * 64;
    unsigned short* dst = (w < 2) ? support : rootbuf;
    #pragma unroll
    for (int mt = 0; mt < 4; ++mt)
        #pragma unroll
        for (int reg = 0; reg < 4; ++reg) {
            const int row = rowBase + mt * 16 + quad * 4 + reg;
            if (row < M) {
                #pragma unroll
                for (int nt = 0; nt < 4; ++nt)
                    dst[(size_t)row * D + cbase + nt * 16 + nl] = f2bf(acc[mt][nt][reg]);
            }
        }
}

// ---- K3: per-bucket (64 rows): gather segs -> LDS row-sort -> reduce -------
__global__ __launch_bounds__(512) void sort_aggregate(
    const int* __restrict__ cntT, const int* __restrict__ offT,
    const int2* __restrict__ sortedB,
    const unsigned short* __restrict__ support,
    const unsigned short* __restrict__ rootbuf,
    float* __restrict__ out, int M, int nbuck, int chunk)
{
    __shared__ int2 stage[BCAP];        // 16 KB
    __shared__ unsigned rowList[BCAP];  // 8 KB
    __shared__ int csum[NCK];           // 2 KB
    __shared__ int offc[NCK];           // 2 KB
    __shared__ int rh[RPB];
    __shared__ int rs[RPB + 1];
    __shared__ int rcur[RPB];
    const int b = blockIdx.x, t = threadIdx.x;

    const int mycnt = cntT[(size_t)t * nbuck + b];   // t in [0,512) == chunk id
    csum[t] = mycnt;
    offc[t] = offT[(size_t)t * nbuck + b];
    __syncthreads();
    for (int off = 1; off < NCK; off <<= 1) {        // inclusive scan, 1/thread
        const int a = (t >= off) ? csum[t - off] : 0;
        __syncthreads();
        csum[t] += a;
        __syncthreads();
    }
    // segment copy: thread t copies chunk t's run (avg ~2 edges)
    {
        int dst = csum[t] - mycnt;
        int lim = min(dst + mycnt, BCAP) - dst;       // defensive (P~0)
        if (lim < 0) lim = 0;
        const int2* src = sortedB + (size_t)t * chunk + offc[t];
        for (int k = 0; k < lim; ++k) stage[dst + k] = src[k];
    }
    if (t < RPB) rh[t] = 0;
    __syncthreads();

    const int T = min(csum[NCK - 1], BCAP);
    for (int e = t; e < T; e += 512) atomicAdd(&rh[stage[e].x >> 16], 1);
    __syncthreads();
    const int myr = (t < RPB) ? rh[t] : 0;
    for (int off = 1; off < RPB; off <<= 1) {         // inclusive scan over rows
        int a = 0;
        if (t < RPB && t >= off) a = rh[t - off];
        __syncthreads();
        if (t < RPB) rh[t] += a;
        __syncthreads();
    }
    if (t < RPB) { rs[t] = rh[t] - myr; rcur[t] = rh[t] - myr; }
    if (t == RPB - 1) rs[RPB] = rh[RPB - 1];
    __syncthreads();
    for (int e = t; e < T; e += 512) {
        const int2 ed = stage[e];
        const int rib = ed.x >> 16;
        const int pos = atomicAdd(&rcur[rib], 1);
        rowList[pos] = ((unsigned)f2bf(__int_as_float(ed.y)) << 16)
                     | (unsigned)(ed.x & 0xFFFF);
    }
    __syncthreads();

    // per-row gather-reduce: wave w handles rows w, w+8, ...
    const int w = t >> 6, lane = t & 63;
    for (int r = w; r < RPB; r += 8) {
        const int row = b * RPB + r;
        if (row >= M) continue;
        const int s = rs[r], e2 = rs[r + 1];
        float ax = 0.f, ay = 0.f;
        int i = s;

        for (; i + 16 <= e2; i += 16) {
            unsigned d[16];
            #pragma unroll
            for (int j = 0; j < 16; ++j) d[j] = rowList[i + j];
            unsigned p[16];
            #pragma unroll
            for (int j = 0; j < 16; ++j)
                p[j] = *(const unsigned*)(support + (size_t)(d[j] & 0xFFFF) * D + lane * 2);
            #pragma unroll
            for (int j = 0; j < 16; ++j) {
                const float v = __builtin_bit_cast(float, d[j] & 0xFFFF0000u);
                ax += __builtin_bit_cast(float, p[j] << 16) * v;
                ay += __builtin_bit_cast(float, p[j] & 0xFFFF0000u) * v;
            }
        }
        if (i + 8 <= e2) {
            unsigned d[8];
            #pragma unroll
            for (int j = 0; j < 8; ++j) d[j] = rowList[i + j];
            unsigned p[8];
            #pragma unroll
            for (int j = 0; j < 8; ++j)
                p[j] = *(const unsigned*)(support + (size_t)(d[j] & 0xFFFF) * D + lane * 2);
            #pragma unroll
            for (int j = 0; j < 8; ++j) {
                const float v = __builtin_bit_cast(float, d[j] & 0xFFFF0000u);
                ax += __builtin_bit_cast(float, p[j] << 16) * v;
                ay += __builtin_bit_cast(float, p[j] & 0xFFFF0000u) * v;
            }
            i += 8;
        }
        if (i < e2) {
            const int m = e2 - i;   // 1..7
            unsigned d[8];
            #pragma unroll
            for (int j = 0; j < 8; ++j) {
                const int idx = i + (j < m ? j : m - 1);
                const unsigned q = rowList[idx];
                d[j] = (j < m) ? q : (q & 0xFFFFu);   // zero val for pads
            }
            unsigned p[8];
            #pragma unroll
            for (int j = 0; j < 8; ++j)
                p[j] = *(const unsigned*)(support + (size_t)(d[j] & 0xFFFF) * D + lane * 2);
            #pragma unroll
            for (int j = 0; j < 8; ++j) {
                const float v = __builtin_bit_cast(float, d[j] & 0xFFFF0000u);
                ax += __builtin_bit_cast(float, p[j] << 16) * v;
                ay += __builtin_bit_cast(float, p[j] & 0xFFFF0000u) * v;
            }
        }

        const unsigned pr = *(const unsigned*)(rootbuf + (size_t)row * D + lane * 2);
        float2v ov;
        ov.x = ax + __builtin_bit_cast(float, pr << 16);
        ov.y = ay + __builtin_bit_cast(float, pr & 0xFFFF0000u);
        __builtin_nontemporal_store(ov, (float2v*)(out + (size_t)row * D + lane * 2));
    }
}

extern "C" void kernel_launch(void* const* d_in, const int* in_sizes, int n_in,
                              void* d_out, int out_size, void* d_ws, size_t ws_size,
                              hipStream_t stream) {
    const float* x     = (const float*)d_in[0];
    const int*   erows = (const int*)d_in[1];
    const int*   ecols = (const int*)d_in[2];
    const float* evals = (const float*)d_in[3];
    const float* W     = (const float*)d_in[4];
    const float* Wr    = (const float*)d_in[5];
    float* out = (float*)d_out;

    const int M = in_sizes[0] / D;   // 50000
    const int E = in_sizes[1];       // 800000

    const int nbuck = (M + RPB - 1) / RPB;         // 782
    const int chunk = (E + NCK - 1) / NCK;         // 1563

    // ws layout
    unsigned short* support = (unsigned short*)d_ws;            // M*D bf16
    unsigned short* rootbuf = support + (size_t)M * D;          // M*D bf16
    unsigned short* Wt      = rootbuf + (size_t)M * D;          // 2*D*D bf16
    int*   cntT    = (int*)(Wt + 2 * D * D);                    // NCK*nbuck
    int*   offT    = cntT + (size_t)NCK * nbuck;                // NCK*nbuck
    int2*  sortedB = (int2*)(offT + (size_t)NCK * nbuck);       // NCK*chunk

    binsort_prep<<<NCK, 256, 0, stream>>>(erows, ecols, evals, W, Wr, Wt,
                                          cntT, offT, sortedB, E, nbuck, chunk);
    gemm_dual<<<(M + 63) / 64, 256, 0, stream>>>(x, Wt, support, rootbuf, M);
    sort_aggregate<<<nbuck, 512, 0, stream>>>(cntT, offT, sortedB,
                                              support, rootbuf, out, M, nbuck, chunk);
}

// Round 9
// 151.447 us; speedup vs baseline: 1.0496x; 1.0496x over previous
//
#include <hip/hip_runtime.h>

#define D 128
#define NCK 512           // edge chunks (binsort blocks in fused K1)
#define RPB 64            // rows per bucket
#define CHUNKCAP 1600     // LDS staging per chunk (chunk <= 1563)
#define BCAP 2048         // per-bucket edge capacity (mean 1024, +32 sigma)
#define SCANW 1024        // padded bucket-scan width (nbuck <= 1024)
#define RAWB 20992        // union LDS: max(2*SCANW*4 + CHUNKCAP*8, 64*136*2)

typedef short short8 __attribute__((ext_vector_type(8)));
typedef float v4f __attribute__((ext_vector_type(4)));
typedef float float2v __attribute__((ext_vector_type(2)));

static __device__ __forceinline__ unsigned short f2bf(float f) {
    unsigned u = __builtin_bit_cast(unsigned, f);
    u = (u + 0x7FFFu + ((u >> 16) & 1u)) >> 16;   // RNE
    return (unsigned short)u;
}

// ---- K0: Wt[n][k] = (W||Wr)[k][n] bf16 (tiny; breaks Wt producer race) ----
__global__ __launch_bounds__(256) void wt_prep(
    const float* __restrict__ W, const float* __restrict__ Wr,
    unsigned short* __restrict__ Wt)
{
    const int gid = (int)blockIdx.x * 256 + (int)threadIdx.x;   // < 32768
    const int k  = gid >> 8;
    const int nn = gid & 255;
    const float v = (nn < D) ? W[k * D + nn] : Wr[k * D + (nn - D)];
    Wt[nn * D + k] = f2bf(v);
}

// ---- K1: fused — blocks [0,NCK): per-chunk binsort; rest: dual GEMM --------
// binsort: LDS counting-sort of chunk by bucket (r>>6) -> contiguous sortedB
//          region + packed table pkT[c][b] = (cnt<<16)|off
// gemm:    support(bf16)=x@W, rootbuf(bf16)=x@Wr (MFMA 16x16x32), reads Wt
__global__ __launch_bounds__(256) void prep_gemm(
    const int* __restrict__ rows, const int* __restrict__ cols,
    const float* __restrict__ vals,
    unsigned* __restrict__ pkT, int2* __restrict__ sortedB,
    const float* __restrict__ x, const unsigned short* __restrict__ Wt,
    unsigned short* __restrict__ support, unsigned short* __restrict__ rootbuf,
    int M, int E, int nbuck, int chunk)
{
    __shared__ __align__(16) char raw[RAWB];
    const int t = threadIdx.x;

    if ((int)blockIdx.x < NCK) {
        // ---------------- binsort branch ----------------
        int* hist = (int*)raw;                       // SCANW
        int* cur  = hist + SCANW;                    // SCANW
        int2* stg = (int2*)(raw + 2 * SCANW * 4);    // CHUNKCAP
        const int c = blockIdx.x;

        #pragma unroll
        for (int j = 0; j < SCANW / 256; ++j) hist[t + j * 256] = 0;
        __syncthreads();

        const int base = c * chunk;
        const int endv = min(base + chunk, E);
        for (int e = base + t; e < endv; e += 256)
            atomicAdd(&hist[rows[e] >> 6], 1);
        __syncthreads();

        int cl_[4];
        #pragma unroll
        for (int j = 0; j < 4; ++j) cl_[j] = hist[t + j * 256];
        // inclusive scan over SCANW entries, 4 per thread (double-sync H-S)
        for (int off = 1; off < SCANW; off <<= 1) {
            int a[4];
            #pragma unroll
            for (int j = 0; j < 4; ++j) {
                const int idx = t + j * 256;
                a[j] = (idx >= off) ? hist[idx - off] : 0;
            }
            __syncthreads();
            #pragma unroll
            for (int j = 0; j < 4; ++j) hist[t + j * 256] += a[j];
            __syncthreads();
        }
        #pragma unroll
        for (int j = 0; j < 4; ++j) {
            const int idx = t + j * 256;
            const int ex = hist[idx] - cl_[j];            // exclusive
            cur[idx] = ex;
            if (idx < nbuck)
                pkT[(size_t)c * nbuck + idx] =
                    ((unsigned)cl_[j] << 16) | (unsigned)ex;
        }
        __syncthreads();

        for (int e = base + t; e < endv; e += 256) {
            const int r  = rows[e];
            const int cc = cols[e];
            const float v = vals[e];
            const int pos = atomicAdd(&cur[r >> 6], 1);
            stg[pos] = make_int2(((r & (RPB - 1)) << 16) | cc, __float_as_int(v));
        }
        __syncthreads();

        const int n = endv - base;
        for (int k = t; k < n; k += 256)
            sortedB[(size_t)base + k] = stg[k];   // contiguous full-line writes
        return;
    }

    // ---------------- GEMM branch ----------------
    unsigned short (*As)[136] = (unsigned short (*)[136])raw;
    const int w = t >> 6;
    const int lane = t & 63;
    const int nl = lane & 15, quad = lane >> 4;
    const int rowBase = ((int)blockIdx.x - NCK) * 64;

    {
        const int r = t & 63;
        const int seg = t >> 6;
        const int row = rowBase + r;
        unsigned short tmp[32];
        if (row < M) {
            const float4* src = (const float4*)(x + (size_t)row * D + seg * 32);
            #pragma unroll
            for (int j = 0; j < 8; ++j) {
                const float4 v = src[j];
                tmp[j * 4 + 0] = f2bf(v.x); tmp[j * 4 + 1] = f2bf(v.y);
                tmp[j * 4 + 2] = f2bf(v.z); tmp[j * 4 + 3] = f2bf(v.w);
            }
        } else {
            #pragma unroll
            for (int j = 0; j < 32; ++j) tmp[j] = 0;
        }
        #pragma unroll
        for (int j = 0; j < 4; ++j)
            *(short8*)&As[r][seg * 32 + j * 8] = *(const short8*)&tmp[j * 8];
    }

    short8 bfrag[4][4];
    {
        const unsigned short* wbase = Wt + (size_t)(w * 64 + nl) * D + quad * 8;
        #pragma unroll
        for (int nt = 0; nt < 4; ++nt)
            #pragma unroll
            for (int c = 0; c < 4; ++c)
                bfrag[c][nt] = *(const short8*)(wbase + (size_t)nt * 16 * D + c * 32);
    }
    __syncthreads();

    v4f acc[4][4] = {};
    #pragma unroll
    for (int c = 0; c < 4; ++c) {
        short8 afr[4];
        #pragma unroll
        for (int mt = 0; mt < 4; ++mt)
            afr[mt] = *(const short8*)&As[mt * 16 + nl][c * 32 + quad * 8];
        #pragma unroll
        for (int mt = 0; mt < 4; ++mt)
            #pragma unroll
            for (int nt = 0; nt < 4; ++nt)
                acc[mt][nt] = __builtin_amdgcn_mfma_f32_16x16x32_bf16(
                    afr[mt], bfrag[c][nt], acc[mt][nt], 0, 0, 0);
    }

    const int cbase = (w & 1) * 64;
    unsigned short* dst = (w < 2) ? support : rootbuf;
    #pragma unroll
    for (int mt = 0; mt < 4; ++mt)
        #pragma unroll
        for (int reg = 0; reg < 4; ++reg) {
            const int row = rowBase + mt * 16 + quad * 4 + reg;
            if (row < M) {
                #pragma unroll
                for (int nt = 0; nt < 4; ++nt)
                    dst[(size_t)row * D + cbase + nt * 16 + nl] = f2bf(acc[mt][nt][reg]);
            }
        }
}

// ---- K2: per-bucket (64 rows): gather segs -> LDS row-sort -> reduce -------
__global__ __launch_bounds__(512) void sort_aggregate(
    const unsigned* __restrict__ pkT, const int2* __restrict__ sortedB,
    const unsigned short* __restrict__ support,
    const unsigned short* __restrict__ rootbuf,
    float* __restrict__ out, int M, int nbuck, int chunk)
{
    __shared__ int2 stage[BCAP];        // 16 KB
    __shared__ unsigned rowList[BCAP];  // 8 KB
    __shared__ int csum[NCK];           // 2 KB
    __shared__ int offc[NCK];           // 2 KB
    __shared__ int rh[RPB];
    __shared__ int rs[RPB + 1];
    __shared__ int rcur[RPB];
    const int b = blockIdx.x, t = threadIdx.x;

    const unsigned pk = pkT[(size_t)t * nbuck + b];   // single strided load
    const int mycnt = (int)(pk >> 16);
    csum[t] = mycnt;
    offc[t] = (int)(pk & 0xFFFFu);
    __syncthreads();
    for (int off = 1; off < NCK; off <<= 1) {        // inclusive scan, 1/thread
        const int a = (t >= off) ? csum[t - off] : 0;
        __syncthreads();
        csum[t] += a;
        __syncthreads();
    }
    // segment copy: thread t copies chunk t's run (avg ~2 edges)
    {
        int dst = csum[t] - mycnt;
        int lim = min(dst + mycnt, BCAP) - dst;       // defensive (P~0)
        if (lim < 0) lim = 0;
        const int2* src = sortedB + (size_t)t * chunk + offc[t];
        for (int k = 0; k < lim; ++k) stage[dst + k] = src[k];
    }
    if (t < RPB) rh[t] = 0;
    __syncthreads();

    const int T = min(csum[NCK - 1], BCAP);
    for (int e = t; e < T; e += 512) atomicAdd(&rh[stage[e].x >> 16], 1);
    __syncthreads();
    const int myr = (t < RPB) ? rh[t] : 0;
    for (int off = 1; off < RPB; off <<= 1) {         // inclusive scan over rows
        int a = 0;
        if (t < RPB && t >= off) a = rh[t - off];
        __syncthreads();
        if (t < RPB) rh[t] += a;
        __syncthreads();
    }
    if (t < RPB) { rs[t] = rh[t] - myr; rcur[t] = rh[t] - myr; }
    if (t == RPB - 1) rs[RPB] = rh[RPB - 1];
    __syncthreads();
    for (int e = t; e < T; e += 512) {
        const int2 ed = stage[e];
        const int rib = ed.x >> 16;
        const int pos = atomicAdd(&rcur[rib], 1);
        rowList[pos] = ((unsigned)f2bf(__int_as_float(ed.y)) << 16)
                     | (unsigned)(ed.x & 0xFFFF);
    }
    __syncthreads();

    // per-row gather-reduce: wave w handles rows w, w+8, ...
    const int w = t >> 6, lane = t & 63;
    for (int r = w; r < RPB; r += 8) {
        const int row = b * RPB + r;
        if (row >= M) continue;
        const int s = rs[r], e2 = rs[r + 1];
        float ax = 0.f, ay = 0.f;
        int i = s;

        for (; i + 16 <= e2; i += 16) {
            unsigned d[16];
            #pragma unroll
            for (int j = 0; j < 16; ++j) d[j] = rowList[i + j];
            unsigned p[16];
            #pragma unroll
            for (int j = 0; j < 16; ++j)
                p[j] = *(const unsigned*)(support + (size_t)(d[j] & 0xFFFF) * D + lane * 2);
            #pragma unroll
            for (int j = 0; j < 16; ++j) {
                const float v = __builtin_bit_cast(float, d[j] & 0xFFFF0000u);
                ax += __builtin_bit_cast(float, p[j] << 16) * v;
                ay += __builtin_bit_cast(float, p[j] & 0xFFFF0000u) * v;
            }
        }
        if (i + 8 <= e2) {
            unsigned d[8];
            #pragma unroll
            for (int j = 0; j < 8; ++j) d[j] = rowList[i + j];
            unsigned p[8];
            #pragma unroll
            for (int j = 0; j < 8; ++j)
                p[j] = *(const unsigned*)(support + (size_t)(d[j] & 0xFFFF) * D + lane * 2);
            #pragma unroll
            for (int j = 0; j < 8; ++j) {
                const float v = __builtin_bit_cast(float, d[j] & 0xFFFF0000u);
                ax += __builtin_bit_cast(float, p[j] << 16) * v;
                ay += __builtin_bit_cast(float, p[j] & 0xFFFF0000u) * v;
            }
            i += 8;
        }
        if (i < e2) {
            const int m = e2 - i;   // 1..7
            unsigned d[8];
            #pragma unroll
            for (int j = 0; j < 8; ++j) {
                const int idx = i + (j < m ? j : m - 1);
                const unsigned q = rowList[idx];
                d[j] = (j < m) ? q : (q & 0xFFFFu);   // zero val for pads
            }
            unsigned p[8];
            #pragma unroll
            for (int j = 0; j < 8; ++j)
                p[j] = *(const unsigned*)(support + (size_t)(d[j] & 0xFFFF) * D + lane * 2);
            #pragma unroll
            for (int j = 0; j < 8; ++j) {
                const float v = __builtin_bit_cast(float, d[j] & 0xFFFF0000u);
                ax += __builtin_bit_cast(float, p[j] << 16) * v;
                ay += __builtin_bit_cast(float, p[j] & 0xFFFF0000u) * v;
            }
        }

        const unsigned pr = *(const unsigned*)(rootbuf + (size_t)row * D + lane * 2);
        float2v ov;
        ov.x = ax + __builtin_bit_cast(float, pr << 16);
        ov.y = ay + __builtin_bit_cast(float, pr & 0xFFFF0000u);
        __builtin_nontemporal_store(ov, (float2v*)(out + (size_t)row * D + lane * 2));
    }
}

extern "C" void kernel_launch(void* const* d_in, const int* in_sizes, int n_in,
                              void* d_out, int out_size, void* d_ws, size_t ws_size,
                              hipStream_t stream) {
    const float* x     = (const float*)d_in[0];
    const int*   erows = (const int*)d_in[1];
    const int*   ecols = (const int*)d_in[2];
    const float* evals = (const float*)d_in[3];
    const float* W     = (const float*)d_in[4];
    const float* Wr    = (const float*)d_in[5];
    float* out = (float*)d_out;

    const int M = in_sizes[0] / D;   // 50000
    const int E = in_sizes[1];       // 800000

    const int nbuck = (M + RPB - 1) / RPB;         // 782
    const int chunk = (E + NCK - 1) / NCK;         // 1563
    const int nGemm = (M + 63) / 64;               // 782

    // ws layout
    unsigned short* support = (unsigned short*)d_ws;            // M*D bf16
    unsigned short* rootbuf = support + (size_t)M * D;          // M*D bf16
    unsigned short* Wt      = rootbuf + (size_t)M * D;          // 2*D*D bf16
    unsigned* pkT   = (unsigned*)(Wt + 2 * D * D);              // NCK*nbuck
    int2*  sortedB  = (int2*)(pkT + (size_t)NCK * nbuck);       // NCK*chunk

    wt_prep<<<128, 256, 0, stream>>>(W, Wr, Wt);
    prep_gemm<<<NCK + nGemm, 256, 0, stream>>>(
        erows, ecols, evals, pkT, sortedB, x, Wt, support, rootbuf,
        M, E, nbuck, chunk);
    sort_aggregate<<<nbuck, 512, 0, stream>>>(pkT, sortedB,
                                              support, rootbuf, out, M, nbuck, chunk);
}